// Round 1
// 81.408 us; speedup vs baseline: 1.0556x; 1.0556x over previous
//
#include <hip/hip_runtime.h>

#define NB 4
#define NP 8
#define NV 2048
#define NE 2048
#define NF 4096
#define BIGV 1.0e10f
#define NCOMBO (NB * NP)       // 32
#define NSPAN 16               // edge spans per block (128 edges each)
#define SPANE 128
#define SPAD (SPANE + 1)       // eds row pad (float4 units): span bases 4 banks apart
#define NVC 16                 // vertex chunks per combo
#define VC 128                 // vertices per chamfer block
#define PPAD (VC + 4)          // part row pad (floats): rows stay 16B-aligned, banks shift by 4

// ws layout:
//   spart[NCOMBO*NVC] (512 floats) : per-(combo,vchunk) masked-sum partials
//   cpart[NCOMBO*NVC] (512 floats) : per-(combo,vchunk) mask-count partials
//   volpart[64]                    : per-(b,facechunk) volume partial sums

// K1: blocks [0,512): chamfer. One block = one (combo, vchunk): complete min over
//     ALL 2048 edges for 128 vertices (16 edge-spans x 16 vertex-groups of 8),
//     cross-span reduce in LDS, masked partial sum out. No 4MB minpart
//     round-trip, no low-occupancy second pass.
//     blocks [512,576): volume face partial sums (unchanged from prior version).
__global__ __launch_bounds__(256) void fused_k1(
    const float* __restrict__ xs, const float* __restrict__ pm,
    const float* __restrict__ edgemaps, const int* __restrict__ elen,
    const int* __restrict__ faces, const void* __restrict__ maskp,
    float* __restrict__ spart, float* __restrict__ cpart,
    float* __restrict__ volpart)
{
    __shared__ float4 eds[NSPAN * SPAD];     // 33 KB: all 2048 edges (ex, ey, e2, pad)
    __shared__ float part[NSPAN][PPAD];      // 8.25 KB: per-span vertex mins
    __shared__ float reds[2], redc[2], redv[4];
    const int tid = threadIdx.x;
    const int bid = blockIdx.x;

    if (bid < 512) {
        const int combo  = bid >> 4;   // b*8 + p
        const int vchunk = bid & 15;
        const int b = combo >> 3;
        const int p = combo & 7;

        // Stage all 2048 edges into LDS (8 per thread), |e|^2 / BIG folded in.
        const int len = elen[combo];
        #pragma unroll
        for (int j = 0; j < 8; j++) {
            const int e = tid + (j << 8);
            float2 exy = ((const float2*)edgemaps)[(size_t)combo * NE + e];
            float e2;
            if (e < len) {
                e2 = exy.x * exy.x + exy.y * exy.y;
            } else {
                exy.x = 0.0f; exy.y = 0.0f; e2 = BIGV;   // ref: d2 -> BIG for invalid e
            }
            eds[(e >> 7) * SPAD + (e & 127)] = make_float4(exy.x, exy.y, e2, 0.0f);
        }

        // Projection matrix for this p (uniform -> scalar loads).
        const float* M = pm + p * 12;
        const float m00 = M[0], m01 = M[1], m02 = M[2],  m03 = M[3];
        const float m10 = M[4], m11 = M[5], m12 = M[6],  m13 = M[7];
        const float m20 = M[8], m21 = M[9], m22 = M[10], m23 = M[11];

        const int vgroup = tid & 15;   // 16 vertex groups x 8 verts = 128 verts
        const int span   = tid >> 4;   // 16 edge spans x 128 edges
        const int v0     = vchunk * VC + (vgroup << 3);

        // Each thread owns 8 vertices: project once (no cross-block redundancy now).
        float px2[8], py2[8], v2[8], mn[8];
        #pragma unroll
        for (int i = 0; i < 8; i++) {
            const int v = v0 + i;
            const float x = xs[((size_t)b * NV + v) * 3 + 0];
            const float y = xs[((size_t)b * NV + v) * 3 + 1];
            const float z = xs[((size_t)b * NV + v) * 3 + 2];
            const float r0 = m00 * x + m01 * y + m02 * z + m03;
            const float r1 = m10 * x + m11 * y + m12 * z + m13;
            const float r2 = m20 * x + m21 * y + m22 * z + m23;
            const float inv = 1.0f / r2;       // r2 ~ 2.0 by construction
            const float px = r0 * inv;
            const float py = r1 * inv;
            px2[i] = -2.0f * px;
            py2[i] = -2.0f * py;
            v2[i]  = px * px + py * py;        // folded out of the min, added back at end
            mn[i]  = 3.0e38f;
        }
        __syncthreads();

        // Hot loop: 128 edges x 8 vertices, 3 VALU/pair (2 fma + min).
        const float4* ep = eds + span * SPAD;
        #pragma unroll 4
        for (int k = 0; k < SPANE; k++) {
            const float4 ed = ep[k];
            #pragma unroll
            for (int i = 0; i < 8; i++)
                mn[i] = fminf(mn[i], fmaf(py2[i], ed.y, fmaf(px2[i], ed.x, ed.z)));
        }

        // Per-span partial mins -> LDS.
        #pragma unroll
        for (int i = 0; i < 8; i++)
            part[span][(vgroup << 3) + i] = mn[i] + v2[i];

        // Sniff boundary_mask dtype (uniform): int32 0/1 words are <=1; packed
        // 1-byte bools read as words exceed 1 with overwhelming probability.
        const unsigned* mw = (const unsigned*)maskp;
        bool as_int = true;
        #pragma unroll
        for (int k = 0; k < 16; k++)
            if (mw[k] > 1u) as_int = false;

        __syncthreads();

        // Cross-span min (16-way) + masked partial sum for this 128-vertex slice.
        float s = 0.0f, c = 0.0f;
        if (tid < VC) {
            float m = part[0][tid];
            #pragma unroll
            for (int sp = 1; sp < NSPAN; sp++)
                m = fminf(m, part[sp][tid]);
            const size_t mix = (size_t)combo * NV + vchunk * VC + tid;
            const float msk = as_int ? (((const int*)maskp)[mix] ? 1.0f : 0.0f)
                                     : (((const unsigned char*)maskp)[mix] ? 1.0f : 0.0f);
            s = m * msk;
            c = msk;
        }
        #pragma unroll
        for (int off = 32; off > 0; off >>= 1) {
            s += __shfl_down(s, off);
            c += __shfl_down(c, off);
        }
        if (tid < VC && (tid & 63) == 0) { reds[tid >> 6] = s; redc[tid >> 6] = c; }
        __syncthreads();
        if (tid == 0) {
            spart[bid] = reds[0] + reds[1];
            cpart[bid] = redc[0] + redc[1];
        }
    } else {
        // Volume: one face per thread, partial sum per block (no atomics).
        const int j = bid - 512;           // 0..63
        const int b = j >> 4;
        const int f = ((j & 15) << 8) + tid;
        const int* fc = faces + ((size_t)b * NF + f) * 3;
        const int i0 = fc[0], i1 = fc[1], i2 = fc[2];
        const float* xb = xs + (size_t)b * NV * 3;
        const float ax = xb[i0 * 3 + 0], ay = xb[i0 * 3 + 1], az = xb[i0 * 3 + 2];
        const float bx = xb[i1 * 3 + 0], by = xb[i1 * 3 + 1], bz = xb[i1 * 3 + 2];
        const float cx = xb[i2 * 3 + 0], cy = xb[i2 * 3 + 1], cz = xb[i2 * 3 + 2];
        const float crx = ay * bz - az * by;
        const float cry = az * bx - ax * bz;
        const float crz = ax * by - ay * bx;
        float fv = (crx * cx + cry * cy + crz * cz) * (1.0f / 6.0f);

        #pragma unroll
        for (int off = 32; off > 0; off >>= 1) fv += __shfl_down(fv, off);
        const int lane = tid & 63, w = tid >> 6;
        if (lane == 0) redv[w] = fv;
        __syncthreads();
        if (tid == 0) volpart[j] = redv[0] + redv[1] + redv[2] + redv[3];
    }
}

// K2: finalize both outputs in one tiny block (was K2+K3).
__global__ __launch_bounds__(64) void fused_k2(
    const float* __restrict__ spart, const float* __restrict__ cpart,
    const float* __restrict__ volpart, const float* __restrict__ tv,
    float* __restrict__ out)
{
    __shared__ float pc[NCOMBO];
    const int tid = threadIdx.x;
    if (tid < NCOMBO) {
        float S = 0.0f, C = 0.0f;
        #pragma unroll
        for (int k = 0; k < NVC; k++) {
            S += spart[tid * NVC + k];
            C += cpart[tid * NVC + k];
        }
        pc[tid] = S / fmaxf(C, 1.0f);
    }
    __syncthreads();
    if (tid < NB) {
        float a = 0.0f;
        #pragma unroll
        for (int p = 0; p < NP; p++) a += pc[tid * NP + p];
        out[tid] = a * (1.0f / NP);
        float vs = 0.0f;
        #pragma unroll
        for (int k = 0; k < 16; k++) vs += volpart[tid * 16 + k];
        const float d = fabsf(vs) - tv[tid];
        out[4 + tid] = d * d;
    }
}

extern "C" void kernel_launch(void* const* d_in, const int* in_sizes, int n_in,
                              void* d_out, int out_size, void* d_ws, size_t ws_size,
                              hipStream_t stream)
{
    const float* xs       = (const float*)d_in[0];
    const float* pm       = (const float*)d_in[1];
    const float* edgemaps = (const float*)d_in[2];
    const int*   elen     = (const int*)d_in[3];
    const void*  mask     = d_in[4];
    const int*   faces    = (const int*)d_in[5];
    const float* tv       = (const float*)d_in[6];
    float* out = (float*)d_out;

    float* spart   = (float*)d_ws;              // 512 floats
    float* cpart   = spart + NCOMBO * NVC;      // 512 floats
    float* volpart = cpart + NCOMBO * NVC;      // 64 floats

    fused_k1<<<dim3(576), dim3(256), 0, stream>>>(xs, pm, edgemaps, elen, faces, mask,
                                                  spart, cpart, volpart);
    fused_k2<<<dim3(1), dim3(64), 0, stream>>>(spart, cpart, volpart, tv, out);
}